// Round 1
// baseline (2623.287 us; speedup 1.0000x reference)
//
#include <hip/hip_runtime.h>
#include <stdint.h>

#define D_MODEL 1024
#define D_HID   4096
#define NEXP    8
#define NTOK    8192
#define TOTROW  (NTOK*2)

typedef unsigned short ushort_t;
typedef __attribute__((ext_vector_type(8))) short short8;
typedef __attribute__((ext_vector_type(4))) float f32x4;

static __device__ __forceinline__ ushort_t f2bf(float f) {
    union { float f; uint32_t u; } v; v.f = f;
    uint32_t u = v.u;
    uint32_t r = (u + 0x7FFFu + ((u >> 16) & 1u)) >> 16;
    return (ushort_t)r;
}
static __device__ __forceinline__ float bf2f(ushort_t h) {
    union { uint32_t u; float f; } v; v.u = ((uint32_t)h) << 16;
    return v.f;
}
static __device__ __forceinline__ float gelu_f(float x) {
    return 0.5f * x * (1.0f + erff(x * 0.70710678118654752f));
}

// ---------------- router: scores + top2 + counts ----------------
__global__ __launch_bounds__(256) void router_kernel(
    const float* __restrict__ x, const float* __restrict__ et,
    int* __restrict__ cnt, int* __restrict__ top2)
{
    __shared__ float lds_et[NEXP * D_MODEL]; // 32 KB
    int t = threadIdx.x;
    #pragma unroll
    for (int i = 0; i < (NEXP * D_MODEL) / 256; ++i)
        lds_et[i * 256 + t] = et[i * 256 + t];
    __syncthreads();

    int lane = t & 63, wv = t >> 6;
    int n = blockIdx.x * 4 + wv;
    double s[NEXP];
    #pragma unroll
    for (int e = 0; e < NEXP; ++e) s[e] = 0.0;
    const float* xr = x + (size_t)n * D_MODEL;
    for (int it = 0; it < D_MODEL / 64; ++it) {
        float xv = xr[it * 64 + lane];
        #pragma unroll
        for (int e = 0; e < NEXP; ++e)
            s[e] += (double)(xv * lds_et[e * D_MODEL + it * 64 + lane]);
    }
    #pragma unroll
    for (int e = 0; e < NEXP; ++e)
        for (int off = 32; off; off >>= 1)
            s[e] += __shfl_xor(s[e], off);

    if (lane == 0) {
        int e1 = 0;
        for (int e = 1; e < NEXP; ++e) if (s[e] > s[e1]) e1 = e;
        int e2 = (e1 == 0) ? 1 : 0;
        for (int e = 0; e < NEXP; ++e) if (e != e1 && s[e] > s[e2]) e2 = e;
        top2[n * 2 + 0] = e1;
        top2[n * 2 + 1] = e2;
        atomicAdd(&cnt[e1], 1);
        atomicAdd(&cnt[e2], 1);
    }
}

__global__ void scan_kernel(const int* __restrict__ cnt, int* __restrict__ base,
                            int* __restrict__ cnt2)
{
    if (threadIdx.x == 0 && blockIdx.x == 0) {
        int acc = 0;
        for (int e = 0; e < NEXP; ++e) { base[e] = acc; acc += cnt[e]; cnt2[e] = 0; }
    }
}

__global__ __launch_bounds__(256) void assign_kernel(
    const int* __restrict__ top2, const int* __restrict__ base,
    int* __restrict__ cnt2, int* __restrict__ rowinfo, int* __restrict__ token_rows)
{
    int n = blockIdx.x * 256 + threadIdx.x;
    if (n >= NTOK) return;
    #pragma unroll
    for (int k = 0; k < 2; ++k) {
        int e = top2[n * 2 + k];
        int slot = atomicAdd(&cnt2[e], 1);
        int row = base[e] + slot;
        rowinfo[row] = n;
        token_rows[n * 2 + k] = row;
    }
}

// ------------- weight transpose+convert: [E][K][N] f32 -> [E][N][K] bf16 -------------
__global__ __launch_bounds__(256) void transpose_kernel(
    const float* __restrict__ in, ushort_t* __restrict__ out, int K, int N)
{
    __shared__ float tile[32][33];
    int e = blockIdx.z;
    int k0 = blockIdx.y * 32, n0 = blockIdx.x * 32;
    const float* ine = in + (size_t)e * K * N;
    ushort_t* oute = out + (size_t)e * N * K;
    int t = threadIdx.x;
    #pragma unroll
    for (int i = 0; i < 4; ++i) {
        int lin = i * 256 + t; int r = lin >> 5, c = lin & 31;
        tile[r][c] = ine[(size_t)(k0 + r) * N + (n0 + c)];
    }
    __syncthreads();
    #pragma unroll
    for (int i = 0; i < 4; ++i) {
        int lin = i * 256 + t; int r = lin >> 5, c = lin & 31;
        oute[(size_t)(n0 + r) * K + (k0 + c)] = f2bf(tile[c][r]);
    }
}

// ---------------- grouped GEMM: C[row][n] = act(A[row][:] @ B[e]^T[n][:] + bias[e][n]) ----------------
// A: rows grouped per expert (base[e] .. base[e]+cnt[e]). BT: [E][Ncols][K] bf16.
template<bool GATHER, bool GELU_ACT>
__global__ __launch_bounds__(256, 2) void moe_gemm(
    const ushort_t* __restrict__ Ah,   // bf16 activations when !GATHER
    const float* __restrict__ Xf,      // fp32 x when GATHER (via rowinfo)
    const ushort_t* __restrict__ BT,
    const float* __restrict__ bias,
    ushort_t* __restrict__ C,
    const int* __restrict__ cnt, const int* __restrict__ base,
    const int* __restrict__ rowinfo,
    int Ncols, int K)
{
    const int e = blockIdx.z;
    const int cnte = cnt[e];
    const int mt = blockIdx.y;
    if (mt * 128 >= cnte) return;
    const int row0 = base[e] + mt * 128;
    const int col0 = blockIdx.x * 128;

    __shared__ __attribute__((aligned(16))) ushort_t Asm[2][128 * 64];
    __shared__ __attribute__((aligned(16))) ushort_t Bsm[2][128 * 64];

    const int t = threadIdx.x;
    const int lane = t & 63;
    const int wv = t >> 6;
    const int wr = (wv >> 1) * 64, wc = (wv & 1) * 64;
    const int l15 = lane & 15, lhi = lane >> 4;

    // staging: thread covers row t>>1, logical 16B-slots (t&1)*4 .. +3
    const int srow = t >> 1;
    const int shalf = (t & 1) * 4;
    const int sxor = srow & 7;

    const float* xrow = nullptr;
    const ushort_t* arow = nullptr;
    if (GATHER) {
        int gr = row0 + srow;
        int tok = rowinfo[gr < TOTROW ? gr : (TOTROW - 1)];
        xrow = Xf + (size_t)tok * K;
    } else {
        arow = Ah + (size_t)(row0 + srow) * K;
    }
    const ushort_t* brow = BT + ((size_t)e * Ncols + col0 + srow) * K;

    f32x4 acc[4][4];
    #pragma unroll
    for (int i = 0; i < 4; ++i)
        #pragma unroll
        for (int j = 0; j < 4; ++j)
            acc[i][j] = (f32x4){0.f, 0.f, 0.f, 0.f};

    auto stage = [&](int buf, int kt) {
        const int k0 = kt * 64;
        #pragma unroll
        for (int s = 0; s < 4; ++s) {
            int sl = shalf + s;
            int ph = sl ^ sxor;
            if (GATHER) {
                float4 f0 = *(const float4*)(xrow + k0 + sl * 8);
                float4 f1 = *(const float4*)(xrow + k0 + sl * 8 + 4);
                short8 v;
                v[0] = (short)f2bf(f0.x); v[1] = (short)f2bf(f0.y);
                v[2] = (short)f2bf(f0.z); v[3] = (short)f2bf(f0.w);
                v[4] = (short)f2bf(f1.x); v[5] = (short)f2bf(f1.y);
                v[6] = (short)f2bf(f1.z); v[7] = (short)f2bf(f1.w);
                *(short8*)&Asm[buf][srow * 64 + ph * 8] = v;
            } else {
                *(uint4*)&Asm[buf][srow * 64 + ph * 8] = *(const uint4*)(arow + k0 + sl * 8);
            }
            *(uint4*)&Bsm[buf][srow * 64 + ph * 8] = *(const uint4*)(brow + k0 + sl * 8);
        }
    };

    const int KT = K / 64;
    int cur = 0;
    stage(0, 0);
    __syncthreads();

    for (int kt = 0; kt < KT; ++kt) {
        if (kt + 1 < KT) stage(cur ^ 1, kt + 1);
        const ushort_t* As = Asm[cur];
        const ushort_t* Bs = Bsm[cur];
        #pragma unroll
        for (int ks = 0; ks < 2; ++ks) {
            short8 af[4], bfr[4];
            #pragma unroll
            for (int i = 0; i < 4; ++i) {
                int r = wr + i * 16 + l15;
                int ph = (ks * 4 + lhi) ^ (r & 7);
                af[i] = *(const short8*)&As[r * 64 + ph * 8];
            }
            #pragma unroll
            for (int j = 0; j < 4; ++j) {
                int r = wc + j * 16 + l15;
                int ph = (ks * 4 + lhi) ^ (r & 7);
                bfr[j] = *(const short8*)&Bs[r * 64 + ph * 8];
            }
            #pragma unroll
            for (int i = 0; i < 4; ++i)
                #pragma unroll
                for (int j = 0; j < 4; ++j)
                    acc[i][j] = __builtin_amdgcn_mfma_f32_16x16x32_bf16(af[i], bfr[j], acc[i][j], 0, 0, 0);
        }
        __syncthreads();
        cur ^= 1;
    }

    // epilogue: C/D layout col=lane&15, row=(lane>>4)*4+q
    #pragma unroll
    for (int j = 0; j < 4; ++j) {
        int colg = col0 + wc + j * 16 + l15;
        float bv = bias[e * Ncols + colg];
        #pragma unroll
        for (int i = 0; i < 4; ++i) {
            #pragma unroll
            for (int q = 0; q < 4; ++q) {
                int rl = mt * 128 + wr + i * 16 + lhi * 4 + q;
                if (rl < cnte) {
                    float v = acc[i][j][q] + bv;
                    if (GELU_ACT) v = gelu_f(v);
                    C[(size_t)(base[e] + rl) * Ncols + colg] = f2bf(v);
                }
            }
        }
    }
}

// ---------------- combine: out[n] = 0.5*(Y[r1] + Y[r2]) ----------------
__global__ __launch_bounds__(256) void combine_kernel(
    const ushort_t* __restrict__ Y, const int* __restrict__ token_rows,
    float* __restrict__ out)
{
    int n = blockIdx.x;
    int t = threadIdx.x;
    int r1 = token_rows[n * 2 + 0], r2 = token_rows[n * 2 + 1];
    const ushort_t* y1 = Y + (size_t)r1 * D_MODEL + t * 4;
    const ushort_t* y2 = Y + (size_t)r2 * D_MODEL + t * 4;
    ushort_t a[4], b[4];
    *(uint2*)a = *(const uint2*)y1;
    *(uint2*)b = *(const uint2*)y2;
    float4 o;
    o.x = 0.5f * (bf2f(a[0]) + bf2f(b[0]));
    o.y = 0.5f * (bf2f(a[1]) + bf2f(b[1]));
    o.z = 0.5f * (bf2f(a[2]) + bf2f(b[2]));
    o.w = 0.5f * (bf2f(a[3]) + bf2f(b[3]));
    *(float4*)(out + (size_t)n * D_MODEL + t * 4) = o;
}

extern "C" void kernel_launch(void* const* d_in, const int* in_sizes, int n_in,
                              void* d_out, int out_size, void* d_ws, size_t ws_size,
                              hipStream_t stream)
{
    const float* x  = (const float*)d_in[0];
    const float* et = (const float*)d_in[1];
    const float* W1 = (const float*)d_in[2];
    const float* b1 = (const float*)d_in[3];
    const float* W2 = (const float*)d_in[4];
    const float* b2 = (const float*)d_in[5];
    const float* W3 = (const float*)d_in[6];
    const float* b3 = (const float*)d_in[7];
    float* out = (float*)d_out;

    char* ws = (char*)d_ws;
    size_t off = 0;
    auto alloc = [&](size_t bytes) -> char* {
        char* p = ws + off;
        off += (bytes + 255) & ~(size_t)255;
        return p;
    };
    int* cnt        = (int*)alloc(NEXP * 4);
    int* basep      = (int*)alloc(NEXP * 4);
    int* cnt2       = (int*)alloc(NEXP * 4);
    int* top2       = (int*)alloc((size_t)NTOK * 2 * 4);
    int* token_rows = (int*)alloc((size_t)NTOK * 2 * 4);
    int* rowinfo    = (int*)alloc((size_t)TOTROW * 4);
    ushort_t* W1T = (ushort_t*)alloc((size_t)NEXP * D_HID * D_MODEL * 2);
    ushort_t* W2T = (ushort_t*)alloc((size_t)NEXP * D_HID * D_HID * 2);
    ushort_t* W3T = (ushort_t*)alloc((size_t)NEXP * D_MODEL * D_HID * 2);
    ushort_t* H1  = (ushort_t*)alloc((size_t)TOTROW * D_HID * 2);
    ushort_t* H2  = (ushort_t*)alloc((size_t)TOTROW * D_HID * 2);
    ushort_t* Yr  = (ushort_t*)alloc((size_t)TOTROW * D_MODEL * 2);
    if (off > ws_size) return; // workspace too small: fail loudly (wrong output)

    hipMemsetAsync(cnt, 0, NEXP * 4, stream);
    router_kernel<<<NTOK / 4, 256, 0, stream>>>(x, et, cnt, top2);
    scan_kernel<<<1, 64, 0, stream>>>(cnt, basep, cnt2);
    assign_kernel<<<NTOK / 256, 256, 0, stream>>>(top2, basep, cnt2, rowinfo, token_rows);

    transpose_kernel<<<dim3(D_HID / 32, D_MODEL / 32, NEXP), 256, 0, stream>>>(W1, W1T, D_MODEL, D_HID);
    transpose_kernel<<<dim3(D_HID / 32, D_HID / 32, NEXP), 256, 0, stream>>>(W2, W2T, D_HID, D_HID);
    transpose_kernel<<<dim3(D_MODEL / 32, D_HID / 32, NEXP), 256, 0, stream>>>(W3, W3T, D_HID, D_MODEL);

    moe_gemm<true, true><<<dim3(D_HID / 128, 64, NEXP), 256, 0, stream>>>(
        nullptr, x, W1T, b1, H1, cnt, basep, rowinfo, D_HID, D_MODEL);
    moe_gemm<false, true><<<dim3(D_HID / 128, 64, NEXP), 256, 0, stream>>>(
        H1, nullptr, W2T, b2, H2, cnt, basep, rowinfo, D_HID, D_HID);
    moe_gemm<false, false><<<dim3(D_MODEL / 128, 64, NEXP), 256, 0, stream>>>(
        H2, nullptr, W3T, b3, Yr, cnt, basep, rowinfo, D_MODEL, D_HID);

    combine_kernel<<<NTOK, 256, 0, stream>>>(Yr, token_rows, out);
}

// Round 2
// 2053.003 us; speedup vs baseline: 1.2778x; 1.2778x over previous
//
#include <hip/hip_runtime.h>
#include <stdint.h>

#define D_MODEL 1024
#define D_HID   4096
#define NEXP    8
#define NTOK    8192
#define TOTROW  (NTOK*2)

typedef unsigned short ushort_t;
typedef __attribute__((ext_vector_type(8))) short short8;
typedef __attribute__((ext_vector_type(4))) float f32x4;

static __device__ __forceinline__ ushort_t f2bf(float f) {
    union { float f; uint32_t u; } v; v.f = f;
    uint32_t u = v.u;
    uint32_t r = (u + 0x7FFFu + ((u >> 16) & 1u)) >> 16;
    return (ushort_t)r;
}
static __device__ __forceinline__ float bf2f(ushort_t h) {
    union { uint32_t u; float f; } v; v.u = ((uint32_t)h) << 16;
    return v.f;
}
static __device__ __forceinline__ float gelu_f(float x) {
    return 0.5f * x * (1.0f + erff(x * 0.70710678118654752f));
}

// async global -> LDS, 16B per lane; LDS dest is wave-uniform base + lane*16
static __device__ __forceinline__ void gload_lds16(const void* g, void* l) {
    __builtin_amdgcn_global_load_lds(
        (const __attribute__((address_space(1))) void*)g,
        (__attribute__((address_space(3))) void*)l,
        16, 0, 0);
}

// ---------------- router: scores + top2 + counts ----------------
__global__ __launch_bounds__(256) void router_kernel(
    const float* __restrict__ x, const float* __restrict__ et,
    int* __restrict__ cnt, int* __restrict__ top2)
{
    __shared__ float lds_et[NEXP * D_MODEL]; // 32 KB
    int t = threadIdx.x;
    #pragma unroll
    for (int i = 0; i < (NEXP * D_MODEL) / 256; ++i)
        lds_et[i * 256 + t] = et[i * 256 + t];
    __syncthreads();

    int lane = t & 63, wv = t >> 6;
    int n = blockIdx.x * 4 + wv;
    double s[NEXP];
    #pragma unroll
    for (int e = 0; e < NEXP; ++e) s[e] = 0.0;
    const float* xr = x + (size_t)n * D_MODEL;
    for (int it = 0; it < D_MODEL / 64; ++it) {
        float xv = xr[it * 64 + lane];
        #pragma unroll
        for (int e = 0; e < NEXP; ++e)
            s[e] += (double)(xv * lds_et[e * D_MODEL + it * 64 + lane]);
    }
    #pragma unroll
    for (int e = 0; e < NEXP; ++e)
        for (int off = 32; off; off >>= 1)
            s[e] += __shfl_xor(s[e], off);

    if (lane == 0) {
        int e1 = 0;
        for (int e = 1; e < NEXP; ++e) if (s[e] > s[e1]) e1 = e;
        int e2 = (e1 == 0) ? 1 : 0;
        for (int e = 0; e < NEXP; ++e) if (e != e1 && s[e] > s[e2]) e2 = e;
        top2[n * 2 + 0] = e1;
        top2[n * 2 + 1] = e2;
        atomicAdd(&cnt[e1], 1);
        atomicAdd(&cnt[e2], 1);
    }
}

__global__ void scan_kernel(const int* __restrict__ cnt, int* __restrict__ base,
                            int* __restrict__ cnt2)
{
    if (threadIdx.x == 0 && blockIdx.x == 0) {
        int acc = 0;
        for (int e = 0; e < NEXP; ++e) { base[e] = acc; acc += cnt[e]; cnt2[e] = 0; }
    }
}

__global__ __launch_bounds__(256) void assign_kernel(
    const int* __restrict__ top2, const int* __restrict__ base,
    int* __restrict__ cnt2, int* __restrict__ rowinfo, int* __restrict__ token_rows)
{
    int n = blockIdx.x * 256 + threadIdx.x;
    if (n >= NTOK) return;
    #pragma unroll
    for (int k = 0; k < 2; ++k) {
        int e = top2[n * 2 + k];
        int slot = atomicAdd(&cnt2[e], 1);
        int row = base[e] + slot;
        rowinfo[row] = n;
        token_rows[n * 2 + k] = row;
    }
}

// ---------------- x fp32 -> bf16 ----------------
__global__ __launch_bounds__(256) void convert_x(
    const float* __restrict__ x, ushort_t* __restrict__ xb)
{
    size_t i = ((size_t)blockIdx.x * 256 + threadIdx.x) * 4;
    float4 f = *(const float4*)(x + i);
    ushort_t o[4];
    o[0] = f2bf(f.x); o[1] = f2bf(f.y); o[2] = f2bf(f.z); o[3] = f2bf(f.w);
    *(uint2*)(xb + i) = *(const uint2*)o;
}

// ------------- weight transpose+convert: [E][K][N] f32 -> [E][N][K] bf16 -------------
__global__ __launch_bounds__(256) void transpose_kernel(
    const float* __restrict__ in, ushort_t* __restrict__ out, int K, int N)
{
    __shared__ float tile[32][33];
    int e = blockIdx.z;
    int k0 = blockIdx.y * 32, n0 = blockIdx.x * 32;
    const float* ine = in + (size_t)e * K * N;
    ushort_t* oute = out + (size_t)e * N * K;
    int t = threadIdx.x;
    #pragma unroll
    for (int i = 0; i < 4; ++i) {
        int lin = i * 256 + t; int r = lin >> 5, c = lin & 31;
        tile[r][c] = ine[(size_t)(k0 + r) * N + (n0 + c)];
    }
    __syncthreads();
    #pragma unroll
    for (int i = 0; i < 4; ++i) {
        int lin = i * 256 + t; int r = lin >> 5, c = lin & 31;
        oute[(size_t)(n0 + r) * K + (k0 + c)] = f2bf(tile[c][r]);
    }
}

// ---------------- grouped GEMM via global_load_lds ----------------
// C[row][n] = act(A[row][:] @ BT[e][n][:] + bias[e][n]); A rows grouped per expert.
// LDS layout: row r (64 bf16 = 8 slots of 16B), slot ph holds source slot ph^(r&7).
// Staging: chunk c = wv*4+i covers rows c*8..c*8+7; lane l -> row c*8+(l>>3),
// LDS slot l&7; per-lane GLOBAL source slot (l&7)^((l>>3)&7)  [rule #21: swizzle
// the source, keep LDS dest linear].
template<bool GATHER, bool GELU_ACT>
__global__ __launch_bounds__(256, 2) void moe_gemm(
    const ushort_t* __restrict__ Ah,   // bf16 activations (xb when GATHER)
    const ushort_t* __restrict__ BT,
    const float* __restrict__ bias,
    ushort_t* __restrict__ C,
    const int* __restrict__ cnt, const int* __restrict__ base,
    const int* __restrict__ rowinfo,
    int Ncols, int K)
{
    const int e = blockIdx.z;
    const int cnte = cnt[e];
    const int mt = blockIdx.y;
    if (mt * 128 >= cnte) return;
    const int row0 = base[e] + mt * 128;
    const int col0 = blockIdx.x * 128;

    __shared__ __attribute__((aligned(16))) ushort_t Asm[2][128 * 64];
    __shared__ __attribute__((aligned(16))) ushort_t Bsm[2][128 * 64];

    const int t = threadIdx.x;
    const int lane = t & 63;
    const int wv = t >> 6;
    const int wr = (wv >> 1) * 64, wc = (wv & 1) * 64;
    const int l15 = lane & 15, lhi = lane >> 4;

    const int lrow = lane >> 3;            // row within 8-row chunk
    const int sl = (lane & 7) ^ lrow;      // pre-swizzled global source slot

    const ushort_t* a_src[4];
    const ushort_t* b_src[4];
    #pragma unroll
    for (int i = 0; i < 4; ++i) {
        int r = (wv * 4 + i) * 8 + lrow;
        int gr = row0 + r; if (gr > TOTROW - 1) gr = TOTROW - 1;
        if (GATHER) {
            int tok = rowinfo[gr];
            a_src[i] = Ah + (size_t)tok * K + sl * 8;
        } else {
            a_src[i] = Ah + (size_t)gr * K + sl * 8;
        }
        b_src[i] = BT + ((size_t)e * Ncols + col0 + r) * K + sl * 8;
    }

    f32x4 acc[4][4];
    #pragma unroll
    for (int i = 0; i < 4; ++i)
        #pragma unroll
        for (int j = 0; j < 4; ++j)
            acc[i][j] = (f32x4){0.f, 0.f, 0.f, 0.f};

    auto stage = [&](int buf, int kt) {
        const int k0 = kt * 64;
        #pragma unroll
        for (int i = 0; i < 4; ++i) {
            gload_lds16(a_src[i] + k0, (void*)&Asm[buf][(wv * 4 + i) * 512]);
            gload_lds16(b_src[i] + k0, (void*)&Bsm[buf][(wv * 4 + i) * 512]);
        }
    };

    const int KT = K / 64;
    int cur = 0;
    stage(0, 0);
    __syncthreads();

    for (int kt = 0; kt < KT; ++kt) {
        if (kt + 1 < KT) stage(cur ^ 1, kt + 1);
        const ushort_t* As = Asm[cur];
        const ushort_t* Bs = Bsm[cur];
        #pragma unroll
        for (int ks = 0; ks < 2; ++ks) {
            short8 af[4], bfr[4];
            #pragma unroll
            for (int i = 0; i < 4; ++i) {
                int r = wr + i * 16 + l15;
                int ph = (ks * 4 + lhi) ^ (r & 7);
                af[i] = *(const short8*)&As[r * 64 + ph * 8];
            }
            #pragma unroll
            for (int j = 0; j < 4; ++j) {
                int r = wc + j * 16 + l15;
                int ph = (ks * 4 + lhi) ^ (r & 7);
                bfr[j] = *(const short8*)&Bs[r * 64 + ph * 8];
            }
            #pragma unroll
            for (int i = 0; i < 4; ++i)
                #pragma unroll
                for (int j = 0; j < 4; ++j)
                    acc[i][j] = __builtin_amdgcn_mfma_f32_16x16x32_bf16(af[i], bfr[j], acc[i][j], 0, 0, 0);
        }
        __syncthreads();
        cur ^= 1;
    }

    // epilogue: C/D layout col=lane&15, row=(lane>>4)*4+q
    #pragma unroll
    for (int j = 0; j < 4; ++j) {
        int colg = col0 + wc + j * 16 + l15;
        float bv = bias[e * Ncols + colg];
        #pragma unroll
        for (int i = 0; i < 4; ++i) {
            #pragma unroll
            for (int q = 0; q < 4; ++q) {
                int rl = mt * 128 + wr + i * 16 + lhi * 4 + q;
                if (rl < cnte) {
                    float v = acc[i][j][q] + bv;
                    if (GELU_ACT) v = gelu_f(v);
                    C[(size_t)(base[e] + rl) * Ncols + colg] = f2bf(v);
                }
            }
        }
    }
}

// ---------------- combine: out[n] = 0.5*(Y[r1] + Y[r2]) ----------------
__global__ __launch_bounds__(256) void combine_kernel(
    const ushort_t* __restrict__ Y, const int* __restrict__ token_rows,
    float* __restrict__ out)
{
    int n = blockIdx.x;
    int t = threadIdx.x;
    int r1 = token_rows[n * 2 + 0], r2 = token_rows[n * 2 + 1];
    const ushort_t* y1 = Y + (size_t)r1 * D_MODEL + t * 4;
    const ushort_t* y2 = Y + (size_t)r2 * D_MODEL + t * 4;
    ushort_t a[4], b[4];
    *(uint2*)a = *(const uint2*)y1;
    *(uint2*)b = *(const uint2*)y2;
    float4 o;
    o.x = 0.5f * (bf2f(a[0]) + bf2f(b[0]));
    o.y = 0.5f * (bf2f(a[1]) + bf2f(b[1]));
    o.z = 0.5f * (bf2f(a[2]) + bf2f(b[2]));
    o.w = 0.5f * (bf2f(a[3]) + bf2f(b[3]));
    *(float4*)(out + (size_t)n * D_MODEL + t * 4) = o;
}

extern "C" void kernel_launch(void* const* d_in, const int* in_sizes, int n_in,
                              void* d_out, int out_size, void* d_ws, size_t ws_size,
                              hipStream_t stream)
{
    const float* x  = (const float*)d_in[0];
    const float* et = (const float*)d_in[1];
    const float* W1 = (const float*)d_in[2];
    const float* b1 = (const float*)d_in[3];
    const float* W2 = (const float*)d_in[4];
    const float* b2 = (const float*)d_in[5];
    const float* W3 = (const float*)d_in[6];
    const float* b3 = (const float*)d_in[7];
    float* out = (float*)d_out;

    char* ws = (char*)d_ws;
    size_t off = 0;
    auto alloc = [&](size_t bytes) -> char* {
        char* p = ws + off;
        off += (bytes + 255) & ~(size_t)255;
        return p;
    };
    int* cnt        = (int*)alloc(NEXP * 4);
    int* basep      = (int*)alloc(NEXP * 4);
    int* cnt2       = (int*)alloc(NEXP * 4);
    int* top2       = (int*)alloc((size_t)NTOK * 2 * 4);
    int* token_rows = (int*)alloc((size_t)NTOK * 2 * 4);
    int* rowinfo    = (int*)alloc((size_t)TOTROW * 4);
    ushort_t* W1T = (ushort_t*)alloc((size_t)NEXP * D_HID * D_MODEL * 2);
    ushort_t* W2T = (ushort_t*)alloc((size_t)NEXP * D_HID * D_HID * 2);
    ushort_t* W3T = (ushort_t*)alloc((size_t)NEXP * D_MODEL * D_HID * 2);
    ushort_t* H1  = (ushort_t*)alloc((size_t)TOTROW * D_HID * 2);
    ushort_t* H2  = (ushort_t*)alloc((size_t)TOTROW * D_HID * 2);
    ushort_t* Yr  = (ushort_t*)alloc((size_t)TOTROW * D_MODEL * 2);
    if (off > ws_size) return; // workspace too small: fail loudly (wrong output)

    // xb (bf16 x) aliases H2: dead by the time GEMM2 writes H2.
    ushort_t* xb = H2;

    hipMemsetAsync(cnt, 0, NEXP * 4, stream);
    router_kernel<<<NTOK / 4, 256, 0, stream>>>(x, et, cnt, top2);
    scan_kernel<<<1, 64, 0, stream>>>(cnt, basep, cnt2);
    assign_kernel<<<NTOK / 256, 256, 0, stream>>>(top2, basep, cnt2, rowinfo, token_rows);

    convert_x<<<(NTOK * D_MODEL) / 1024, 256, 0, stream>>>(x, xb);

    transpose_kernel<<<dim3(D_HID / 32, D_MODEL / 32, NEXP), 256, 0, stream>>>(W1, W1T, D_MODEL, D_HID);
    transpose_kernel<<<dim3(D_HID / 32, D_HID / 32, NEXP), 256, 0, stream>>>(W2, W2T, D_HID, D_HID);
    transpose_kernel<<<dim3(D_MODEL / 32, D_HID / 32, NEXP), 256, 0, stream>>>(W3, W3T, D_HID, D_MODEL);

    moe_gemm<true, true><<<dim3(D_HID / 128, 64, NEXP), 256, 0, stream>>>(
        xb, W1T, b1, H1, cnt, basep, rowinfo, D_HID, D_MODEL);
    moe_gemm<false, true><<<dim3(D_HID / 128, 64, NEXP), 256, 0, stream>>>(
        H1, W2T, b2, H2, cnt, basep, rowinfo, D_HID, D_HID);
    moe_gemm<false, false><<<dim3(D_MODEL / 128, 64, NEXP), 256, 0, stream>>>(
        H2, W3T, b3, Yr, cnt, basep, rowinfo, D_MODEL, D_HID);

    combine_kernel<<<NTOK, 256, 0, stream>>>(Yr, token_rows, out);
}

// Round 3
// 1968.445 us; speedup vs baseline: 1.3327x; 1.0430x over previous
//
#include <hip/hip_runtime.h>
#include <stdint.h>

#define D_MODEL 1024
#define D_HID   4096
#define NEXP    8
#define NTOK    8192
#define TOTROW  (NTOK*2)

typedef unsigned short ushort_t;
typedef __attribute__((ext_vector_type(8))) short short8;
typedef __attribute__((ext_vector_type(4))) float f32x4;

static __device__ __forceinline__ ushort_t f2bf(float f) {
    union { float f; uint32_t u; } v; v.f = f;
    uint32_t u = v.u;
    uint32_t r = (u + 0x7FFFu + ((u >> 16) & 1u)) >> 16;
    return (ushort_t)r;
}
static __device__ __forceinline__ float bf2f(ushort_t h) {
    union { uint32_t u; float f; } v; v.u = ((uint32_t)h) << 16;
    return v.f;
}
static __device__ __forceinline__ float gelu_f(float x) {
    return 0.5f * x * (1.0f + erff(x * 0.70710678118654752f));
}

static __device__ __forceinline__ void gload_lds16(const void* g, void* l) {
    __builtin_amdgcn_global_load_lds(
        (const __attribute__((address_space(1))) void*)g,
        (__attribute__((address_space(3))) void*)l,
        16, 0, 0);
}

// ---------------- router ----------------
__global__ __launch_bounds__(256) void router_kernel(
    const float* __restrict__ x, const float* __restrict__ et,
    int* __restrict__ cnt, int* __restrict__ top2)
{
    __shared__ float lds_et[NEXP * D_MODEL];
    int t = threadIdx.x;
    #pragma unroll
    for (int i = 0; i < (NEXP * D_MODEL) / 256; ++i)
        lds_et[i * 256 + t] = et[i * 256 + t];
    __syncthreads();

    int lane = t & 63, wv = t >> 6;
    int n = blockIdx.x * 4 + wv;
    double s[NEXP];
    #pragma unroll
    for (int e = 0; e < NEXP; ++e) s[e] = 0.0;
    const float* xr = x + (size_t)n * D_MODEL;
    for (int it = 0; it < D_MODEL / 64; ++it) {
        float xv = xr[it * 64 + lane];
        #pragma unroll
        for (int e = 0; e < NEXP; ++e)
            s[e] += (double)(xv * lds_et[e * D_MODEL + it * 64 + lane]);
    }
    #pragma unroll
    for (int e = 0; e < NEXP; ++e)
        for (int off = 32; off; off >>= 1)
            s[e] += __shfl_xor(s[e], off);

    if (lane == 0) {
        int e1 = 0;
        for (int e = 1; e < NEXP; ++e) if (s[e] > s[e1]) e1 = e;
        int e2 = (e1 == 0) ? 1 : 0;
        for (int e = 0; e < NEXP; ++e) if (e != e1 && s[e] > s[e2]) e2 = e;
        top2[n * 2 + 0] = e1;
        top2[n * 2 + 1] = e2;
        atomicAdd(&cnt[e1], 1);
        atomicAdd(&cnt[e2], 1);
    }
}

__global__ void scan_kernel(const int* __restrict__ cnt, int* __restrict__ base,
                            int* __restrict__ cnt2)
{
    if (threadIdx.x == 0 && blockIdx.x == 0) {
        int acc = 0;
        for (int e = 0; e < NEXP; ++e) { base[e] = acc; acc += cnt[e]; cnt2[e] = 0; }
    }
}

__global__ __launch_bounds__(256) void assign_kernel(
    const int* __restrict__ top2, const int* __restrict__ base,
    int* __restrict__ cnt2, int* __restrict__ rowinfo, int* __restrict__ token_rows)
{
    int n = blockIdx.x * 256 + threadIdx.x;
    if (n >= NTOK) return;
    #pragma unroll
    for (int k = 0; k < 2; ++k) {
        int e = top2[n * 2 + k];
        int slot = atomicAdd(&cnt2[e], 1);
        int row = base[e] + slot;
        rowinfo[row] = n;
        token_rows[n * 2 + k] = row;
    }
}

// ---------------- x fp32 -> bf16 ----------------
__global__ __launch_bounds__(256) void convert_x(
    const float* __restrict__ x, ushort_t* __restrict__ xb)
{
    size_t i = ((size_t)blockIdx.x * 256 + threadIdx.x) * 4;
    float4 f = *(const float4*)(x + i);
    ushort_t o[4];
    o[0] = f2bf(f.x); o[1] = f2bf(f.y); o[2] = f2bf(f.z); o[3] = f2bf(f.w);
    *(uint2*)(xb + i) = *(const uint2*)o;
}

// ------------- weight transpose+convert: [E][K][N] f32 -> [E][N][K] bf16 -------------
__global__ __launch_bounds__(256) void transpose_kernel(
    const float* __restrict__ in, ushort_t* __restrict__ out, int K, int N)
{
    __shared__ float tile[32][33];
    int e = blockIdx.z;
    int k0 = blockIdx.y * 32, n0 = blockIdx.x * 32;
    const float* ine = in + (size_t)e * K * N;
    ushort_t* oute = out + (size_t)e * N * K;
    int t = threadIdx.x;
    #pragma unroll
    for (int i = 0; i < 4; ++i) {
        int lin = i * 256 + t; int r = lin >> 5, c = lin & 31;
        tile[r][c] = ine[(size_t)(k0 + r) * N + (n0 + c)];
    }
    __syncthreads();
    #pragma unroll
    for (int i = 0; i < 4; ++i) {
        int lin = i * 256 + t; int r = lin >> 5, c = lin & 31;
        oute[(size_t)(n0 + r) * K + (k0 + c)] = f2bf(tile[c][r]);
    }
}

// ================= grouped GEMM, 256x256 tile, BK=64, 8-phase counted-vmcnt =================
// C[row][n] = act(A[row][:] @ BT[e][n][:] + bias[e][n]); A rows grouped per expert.
// LDS[buf][row][slot]: slot s holds global k-slot s^(row&7) (bank-conflict-free ds_read_b128,
// achieved by pre-swizzling the per-lane GLOBAL source; LDS dest stays linear).
// Phases per 2 K-tiles: quadrants (mh,nh) = (0,0)(0,1)(1,1)(1,0) on buf0 then buf1.
// Staging units: A-quarters (mh: 64 rows x 2 halves), B-eighths (nh: 32-col strips).
// Each unit staged >=1 barrier after its last LDS read (WAR), vmcnt(4) @ph4/ph8
// guarantees landing >=2 phases before first read (RAW). Final iter: vmcnt(0) @ph4.

#define VW4 asm volatile("s_waitcnt vmcnt(4)" ::: "memory")
#define VW0 asm volatile("s_waitcnt vmcnt(0)" ::: "memory")
#define VNO ((void)0)

#define PHASE(BUF, MH, NH, LOADA, LOADB, BREG, STAGE_STMT, TAIL_STMT)           \
  do {                                                                          \
    if (LOADA) {                                                                \
      _Pragma("unroll") for (int mi = 0; mi < 4; ++mi)                          \
      _Pragma("unroll") for (int ks = 0; ks < 2; ++ks)                          \
        areg[mi][ks] = *(const short8*)&As[BUF][wm*128 + (MH)*64 + mi*16 + l15][((ks*4 + lhi) ^ key) * 8]; \
    }                                                                           \
    if (LOADB) {                                                                \
      _Pragma("unroll") for (int ni = 0; ni < 2; ++ni)                          \
      _Pragma("unroll") for (int ks = 0; ks < 2; ++ks)                          \
        BREG[ni][ks] = *(const short8*)&Bs[BUF][wn*64 + (NH)*32 + ni*16 + l15][((ks*4 + lhi) ^ key) * 8]; \
    }                                                                           \
    STAGE_STMT;                                                                 \
    __builtin_amdgcn_s_barrier();                                               \
    asm volatile("s_waitcnt lgkmcnt(0)" ::: "memory");                          \
    __builtin_amdgcn_s_setprio(1);                                              \
    _Pragma("unroll") for (int mi = 0; mi < 4; ++mi)                            \
    _Pragma("unroll") for (int ni = 0; ni < 2; ++ni)                            \
    _Pragma("unroll") for (int ks = 0; ks < 2; ++ks)                            \
      acc[(MH)*4 + mi][(NH)*2 + ni] = __builtin_amdgcn_mfma_f32_16x16x32_bf16(  \
          areg[mi][ks], BREG[ni][ks], acc[(MH)*4 + mi][(NH)*2 + ni], 0, 0, 0);  \
    __builtin_amdgcn_s_setprio(0);                                              \
    TAIL_STMT;                                                                  \
    __builtin_amdgcn_s_barrier();                                               \
  } while (0)

template<bool GATHER, bool GELU_ACT>
__global__ __launch_bounds__(512, 2) void moe_gemm8(
    const ushort_t* __restrict__ Ah,
    const ushort_t* __restrict__ BT,
    const float* __restrict__ bias,
    ushort_t* __restrict__ C,
    const int* __restrict__ cnt, const int* __restrict__ basep,
    const int* __restrict__ rowinfo,
    int Ncols, int K)
{
    const int e = blockIdx.z;
    const int cnte = cnt[e];
    const int mt = blockIdx.y;
    if (mt * 256 >= cnte) return;
    const int base_e = basep[e];
    const int row0 = base_e + mt * 256;
    const int col0 = blockIdx.x * 256;

    __shared__ __attribute__((aligned(16))) ushort_t As[2][256][64]; // 64 KB
    __shared__ __attribute__((aligned(16))) ushort_t Bs[2][256][64]; // 64 KB

    const int t = threadIdx.x;
    const int lane = t & 63;
    const int wv = t >> 6;       // 0..7
    const int wm = wv >> 2;      // 0..1
    const int wn = wv & 3;       // 0..3
    const int l15 = lane & 15, lhi = lane >> 4;
    const int key = l15 & 7;
    const int lr8 = lane >> 3;                 // 0..7
    const int sl  = (lane & 7) ^ lr8;          // pre-swizzled global k-slot

    // staging source pointers (k-offset added per stage call)
    const ushort_t* aP[2][2];
    #pragma unroll
    for (int mh = 0; mh < 2; ++mh)
        #pragma unroll
        for (int c = 0; c < 2; ++c) {
            int tr = mh * 64 + wv * 8 + lr8 + c * 128;
            int gr = row0 + tr; if (gr > TOTROW - 1) gr = TOTROW - 1;
            size_t rowid = GATHER ? (size_t)rowinfo[gr] : (size_t)gr;
            aP[mh][c] = Ah + rowid * K + sl * 8;
        }
    const ushort_t* bP[2][2];
    #pragma unroll
    for (int nh = 0; nh < 2; ++nh)
        #pragma unroll
        for (int c = 0; c < 2; ++c) {
            int tr = (wv >> 2) * 64 + nh * 32 + (wv & 3) * 8 + lr8 + c * 128;
            bP[nh][c] = BT + ((size_t)e * Ncols + col0 + tr) * K + sl * 8;
        }

    // per-wave-uniform LDS staging row bases
    const int arb = wv * 8;                               // + mh*64 (+128 for c=1)
    const int brb = (wv >> 2) * 64 + (wv & 3) * 8;        // + nh*32 (+128 for c=1)

    auto stageA = [&](int buf, int mh, int kt) {
        gload_lds16(aP[mh][0] + kt * 64, (void*)&As[buf][mh * 64 + arb][0]);
        gload_lds16(aP[mh][1] + kt * 64, (void*)&As[buf][128 + mh * 64 + arb][0]);
    };
    auto stageB = [&](int buf, int nh, int kt) {
        gload_lds16(bP[nh][0] + kt * 64, (void*)&Bs[buf][nh * 32 + brb][0]);
        gload_lds16(bP[nh][1] + kt * 64, (void*)&Bs[buf][128 + nh * 32 + brb][0]);
    };

    f32x4 acc[8][4];
    #pragma unroll
    for (int i = 0; i < 8; ++i)
        #pragma unroll
        for (int j = 0; j < 4; ++j)
            acc[i][j] = (f32x4){0.f, 0.f, 0.f, 0.f};

    short8 areg[4][2], breg0[2][2], breg1[2][2];

    const int KT = K / 64;
    const int NIT = KT / 2;

    // prologue: buf0 fully (kt 0) + buf1 early units (kt 1)
    stageA(0, 0, 0); stageA(0, 1, 0); stageB(0, 0, 0); stageB(0, 1, 0);
    stageA(1, 0, 1); stageB(1, 1, 1);
    VW4;   // all of buf0 landed (last 2 stage-slots = buf1's may fly)
    __builtin_amdgcn_s_barrier();

    for (int i2 = 0; i2 < NIT - 1; ++i2) {
        const int kt1 = 2 * i2 + 1, kt2 = 2 * i2 + 2, kt3 = 2 * i2 + 3;
        PHASE(0, 0, 0, true,  true,  breg0, stageA(1, 1, kt1), VNO); // ph1
        PHASE(0, 0, 1, false, true,  breg1, stageB(1, 0, kt1), VNO); // ph2
        PHASE(0, 1, 1, true,  false, breg1, stageA(0, 0, kt2), VNO); // ph3
        PHASE(0, 1, 0, false, false, breg0, stageB(0, 1, kt2), VW4); // ph4
        PHASE(1, 0, 0, true,  true,  breg0, stageA(0, 1, kt2), VNO); // ph5
        PHASE(1, 0, 1, false, true,  breg1, stageB(0, 0, kt2), VNO); // ph6
        PHASE(1, 1, 1, true,  false, breg1, stageA(1, 0, kt3), VNO); // ph7
        PHASE(1, 1, 0, false, false, breg0, stageB(1, 1, kt3), VW4); // ph8
    }
    {   // final iteration: no next-tile staging; drain before buf1 compute
        const int kt1 = 2 * (NIT - 1) + 1;
        PHASE(0, 0, 0, true,  true,  breg0, stageA(1, 1, kt1), VNO);
        PHASE(0, 0, 1, false, true,  breg1, stageB(1, 0, kt1), VNO);
        PHASE(0, 1, 1, true,  false, breg1, VNO,               VNO);
        PHASE(0, 1, 0, false, false, breg0, VNO,               VW0);
        PHASE(1, 0, 0, true,  true,  breg0, VNO,               VNO);
        PHASE(1, 0, 1, false, true,  breg1, VNO,               VNO);
        PHASE(1, 1, 1, true,  false, breg1, VNO,               VNO);
        PHASE(1, 1, 0, false, false, breg0, VNO,               VNO);
    }

    // epilogue: C/D layout col=lane&15, row=(lane>>4)*4+q
    #pragma unroll
    for (int n = 0; n < 4; ++n) {
        int colg = col0 + wn * 64 + n * 16 + l15;
        float bv = bias[e * Ncols + colg];
        #pragma unroll
        for (int m = 0; m < 8; ++m) {
            #pragma unroll
            for (int q = 0; q < 4; ++q) {
                int rl = mt * 256 + wm * 128 + m * 16 + lhi * 4 + q;
                if (rl < cnte) {
                    float v = acc[m][n][q] + bv;
                    if (GELU_ACT) v = gelu_f(v);
                    C[(size_t)(base_e + rl) * Ncols + colg] = f2bf(v);
                }
            }
        }
    }
}

// ---------------- combine: out[n] = 0.5*(Y[r1] + Y[r2]) ----------------
__global__ __launch_bounds__(256) void combine_kernel(
    const ushort_t* __restrict__ Y, const int* __restrict__ token_rows,
    float* __restrict__ out)
{
    int n = blockIdx.x;
    int t = threadIdx.x;
    int r1 = token_rows[n * 2 + 0], r2 = token_rows[n * 2 + 1];
    const ushort_t* y1 = Y + (size_t)r1 * D_MODEL + t * 4;
    const ushort_t* y2 = Y + (size_t)r2 * D_MODEL + t * 4;
    ushort_t a[4], b[4];
    *(uint2*)a = *(const uint2*)y1;
    *(uint2*)b = *(const uint2*)y2;
    float4 o;
    o.x = 0.5f * (bf2f(a[0]) + bf2f(b[0]));
    o.y = 0.5f * (bf2f(a[1]) + bf2f(b[1]));
    o.z = 0.5f * (bf2f(a[2]) + bf2f(b[2]));
    o.w = 0.5f * (bf2f(a[3]) + bf2f(b[3]));
    *(float4*)(out + (size_t)n * D_MODEL + t * 4) = o;
}

extern "C" void kernel_launch(void* const* d_in, const int* in_sizes, int n_in,
                              void* d_out, int out_size, void* d_ws, size_t ws_size,
                              hipStream_t stream)
{
    const float* x  = (const float*)d_in[0];
    const float* et = (const float*)d_in[1];
    const float* W1 = (const float*)d_in[2];
    const float* b1 = (const float*)d_in[3];
    const float* W2 = (const float*)d_in[4];
    const float* b2 = (const float*)d_in[5];
    const float* W3 = (const float*)d_in[6];
    const float* b3 = (const float*)d_in[7];
    float* out = (float*)d_out;

    char* ws = (char*)d_ws;
    size_t off = 0;
    auto alloc = [&](size_t bytes) -> char* {
        char* p = ws + off;
        off += (bytes + 255) & ~(size_t)255;
        return p;
    };
    int* cnt        = (int*)alloc(NEXP * 4);
    int* basep      = (int*)alloc(NEXP * 4);
    int* cnt2       = (int*)alloc(NEXP * 4);
    int* top2       = (int*)alloc((size_t)NTOK * 2 * 4);
    int* token_rows = (int*)alloc((size_t)NTOK * 2 * 4);
    int* rowinfo    = (int*)alloc((size_t)TOTROW * 4);
    ushort_t* W1T = (ushort_t*)alloc((size_t)NEXP * D_HID * D_MODEL * 2);
    ushort_t* W2T = (ushort_t*)alloc((size_t)NEXP * D_HID * D_HID * 2);
    ushort_t* W3T = (ushort_t*)alloc((size_t)NEXP * D_MODEL * D_HID * 2);
    ushort_t* H1  = (ushort_t*)alloc((size_t)TOTROW * D_HID * 2);
    ushort_t* H2  = (ushort_t*)alloc((size_t)TOTROW * D_HID * 2);
    ushort_t* Yr  = (ushort_t*)alloc((size_t)TOTROW * D_MODEL * 2);
    if (off > ws_size) return; // workspace too small: fail loudly (wrong output)

    // xb (bf16 x) aliases H2: dead until GEMM2 writes H2.
    ushort_t* xb = H2;

    hipMemsetAsync(cnt, 0, NEXP * 4, stream);
    router_kernel<<<NTOK / 4, 256, 0, stream>>>(x, et, cnt, top2);
    scan_kernel<<<1, 64, 0, stream>>>(cnt, basep, cnt2);
    assign_kernel<<<NTOK / 256, 256, 0, stream>>>(top2, basep, cnt2, rowinfo, token_rows);

    convert_x<<<(NTOK * D_MODEL) / 1024, 256, 0, stream>>>(x, xb);

    transpose_kernel<<<dim3(D_HID / 32, D_MODEL / 32, NEXP), 256, 0, stream>>>(W1, W1T, D_MODEL, D_HID);
    transpose_kernel<<<dim3(D_HID / 32, D_HID / 32, NEXP), 256, 0, stream>>>(W2, W2T, D_HID, D_HID);
    transpose_kernel<<<dim3(D_MODEL / 32, D_HID / 32, NEXP), 256, 0, stream>>>(W3, W3T, D_HID, D_MODEL);

    moe_gemm8<true, true><<<dim3(D_HID / 256, 32, NEXP), 512, 0, stream>>>(
        xb, W1T, b1, H1, cnt, basep, rowinfo, D_HID, D_MODEL);
    moe_gemm8<false, true><<<dim3(D_HID / 256, 32, NEXP), 512, 0, stream>>>(
        H1, W2T, b2, H2, cnt, basep, rowinfo, D_HID, D_HID);
    moe_gemm8<false, false><<<dim3(D_MODEL / 256, 32, NEXP), 512, 0, stream>>>(
        H2, W3T, b3, Yr, cnt, basep, rowinfo, D_MODEL, D_HID);

    combine_kernel<<<NTOK, 256, 0, stream>>>(Yr, token_rows, out);
}